// Round 4
// baseline (118.750 us; speedup 1.0000x reference)
//
#include <hip/hip_runtime.h>
#include <hip/hip_cooperative_groups.h>

namespace cg = cooperative_groups;

#define NODES   100000
#define DIM     128
#define NEDGES  1600000   // 4 * 400000
#define NQUADS  (NEDGES / 4)

#define LOG2E 1.44269504088896340736f

#define NBLK  1024
#define NTHR  256
#define TOTAL (NBLK * NTHR)            // 262144 threads
#define NODES_PER_SWEEP (TOTAL / 32)   // 8192 nodes per grid sweep

// clang-native vector types (accepted by __builtin_nontemporal_*)
typedef int   v4i __attribute__((ext_vector_type(4)));
typedef float v4f __attribute__((ext_vector_type(4)));

__device__ __forceinline__ float fast_sigmoid(float x) {
    return __builtin_amdgcn_rcpf(1.0f + __builtin_amdgcn_exp2f(-x * LOG2E));
}

// Fused: phase 1 (node projections) -> grid.sync -> phase 2 (edge scores).
// src/dst indices are preloaded into registers BEFORE phase 1's h stream, so
// their HBM latency hides under it. pu/pv (800 KB) stay L2-resident for the
// phase-2 gathers.
__global__ __launch_bounds__(NTHR, 4) void fused_kernel(
    const float* __restrict__ h,
    const int*   __restrict__ src,
    const int*   __restrict__ dst,
    const float* __restrict__ W,      // 256 floats: Wu | Wv
    const float* __restrict__ bias_ptr,
    float* __restrict__ pu,
    float* __restrict__ pv,
    float* __restrict__ out)
{
    const int tid  = blockIdx.x * NTHR + threadIdx.x;
    const int lane = threadIdx.x & 31;

    // Per-lane weight slices (16B each), kept in registers for all sweeps.
    const v4f wu = *reinterpret_cast<const v4f*>(W + lane * 4);
    const v4f wv = *reinterpret_cast<const v4f*>(W + DIM + lane * 4);
    const float b = bias_ptr[0];

    // ---- Preload phase-2 edge indices (2 grid-stride iters, predicated). ----
    // These 4 loads stay in flight / in regs across all of phase 1.
    const int i0 = tid;            // always < NQUADS (262144 < 400000)
    const int i1 = tid + TOTAL;    // valid iff < NQUADS
    v4i s0_ = __builtin_nontemporal_load(reinterpret_cast<const v4i*>(src) + i0);
    v4i d0_ = __builtin_nontemporal_load(reinterpret_cast<const v4i*>(dst) + i0);
    v4i s1_{}, d1_{};
    const bool has1 = (i1 < NQUADS);
    if (has1) {
        s1_ = __builtin_nontemporal_load(reinterpret_cast<const v4i*>(src) + i1);
        d1_ = __builtin_nontemporal_load(reinterpret_cast<const v4i*>(dst) + i1);
    }

    // ---- Phase 1: pu[n] = h[n].Wu, pv[n] = h[n].Wv + b ----
    #pragma unroll 2
    for (int n = tid >> 5; n < NODES; n += NODES_PER_SWEEP) {
        const v4f hv = __builtin_nontemporal_load(
            reinterpret_cast<const v4f*>(h + (size_t)n * DIM + lane * 4));

        float su = hv.x * wu.x + hv.y * wu.y + hv.z * wu.z + hv.w * wu.w;
        float sv = hv.x * wv.x + hv.y * wv.y + hv.z * wv.z + hv.w * wv.w;

        #pragma unroll
        for (int off = 16; off >= 1; off >>= 1) {
            su += __shfl_xor(su, off);
            sv += __shfl_xor(sv, off);
        }

        if (lane == 0) {
            pu[n] = su;
            pv[n] = sv + b;
        }
    }

    cg::this_grid().sync();

    // ---- Phase 2: out[e] = sigmoid(pu[src[e]] + pv[dst[e]]) ----
    {
        float a0 = pu[s0_.x], c0 = pv[d0_.x];
        float a1 = pu[s0_.y], c1 = pv[d0_.y];
        float a2 = pu[s0_.z], c2 = pv[d0_.z];
        float a3 = pu[s0_.w], c3 = pv[d0_.w];
        v4f r;
        r.x = fast_sigmoid(a0 + c0);
        r.y = fast_sigmoid(a1 + c1);
        r.z = fast_sigmoid(a2 + c2);
        r.w = fast_sigmoid(a3 + c3);
        __builtin_nontemporal_store(r, reinterpret_cast<v4f*>(out) + i0);
    }
    if (has1) {
        float a0 = pu[s1_.x], c0 = pv[d1_.x];
        float a1 = pu[s1_.y], c1 = pv[d1_.y];
        float a2 = pu[s1_.z], c2 = pv[d1_.z];
        float a3 = pu[s1_.w], c3 = pv[d1_.w];
        v4f r;
        r.x = fast_sigmoid(a0 + c0);
        r.y = fast_sigmoid(a1 + c1);
        r.z = fast_sigmoid(a2 + c2);
        r.w = fast_sigmoid(a3 + c3);
        __builtin_nontemporal_store(r, reinterpret_cast<v4f*>(out) + i1);
    }
}

extern "C" void kernel_launch(void* const* d_in, const int* in_sizes, int n_in,
                              void* d_out, int out_size, void* d_ws, size_t ws_size,
                              hipStream_t stream) {
    const float* h    = (const float*)d_in[0];
    const int*   src  = (const int*)d_in[1];
    const int*   dst  = (const int*)d_in[2];
    const float* W    = (const float*)d_in[3];   // (1, 256)
    const float* bias = (const float*)d_in[4];   // (1,)
    float* out = (float*)d_out;

    float* pu = (float*)d_ws;                    // NODES floats
    float* pv = pu + NODES;                      // NODES floats

    void* args[] = {
        (void*)&h, (void*)&src, (void*)&dst, (void*)&W, (void*)&bias,
        (void*)&pu, (void*)&pv, (void*)&out
    };
    hipLaunchCooperativeKernel((const void*)fused_kernel,
                               dim3(NBLK), dim3(NTHR), args, 0, stream);
}

// Round 5
// 32.752 us; speedup vs baseline: 3.6257x; 3.6257x over previous
//
#include <hip/hip_runtime.h>
#include <math.h>

#define NODES   100000
#define DIM     128
#define NEDGES  1600000          // 4 * 400000
#define NQUADS  (NEDGES / 4)     // 400000
#define HALFQ   (NQUADS / 2)     // 200000

#define LOG2E 1.44269504088896340736f

// clang-native vector types (accepted by __builtin_nontemporal_*)
typedef int   v4i __attribute__((ext_vector_type(4)));
typedef float v4f __attribute__((ext_vector_type(4)));

__device__ __forceinline__ float fast_sigmoid(float x) {
    return __builtin_amdgcn_rcpf(1.0f + __builtin_amdgcn_exp2f(-x * LOG2E));
}

// Phase 1: per-node projections pu[n] = dot(h[n], Wu), pv[n] = dot(h[n], Wv) + bias.
// 32 lanes cooperate per node; each lane loads one float4 (16B). A 64-lane wave
// covers 2 consecutive nodes = 1024 contiguous bytes -> fully coalesced.
// NOTE: normal (cached) loads — h is L3-resident across graph replays; NT hints
// would force HBM re-fetch (R4 lesson).
__global__ __launch_bounds__(256) void node_proj_kernel(
    const float* __restrict__ h,
    const float* __restrict__ W,      // 256 floats: Wu = W[0:128], Wv = W[128:256]
    const float* __restrict__ bias_ptr,
    float* __restrict__ pu,
    float* __restrict__ pv,
    int n_nodes)
{
    int tid  = blockIdx.x * blockDim.x + threadIdx.x;
    int lane = tid & 31;
    int node = tid >> 5;
    if (node >= n_nodes) return;

    const v4f hv = *reinterpret_cast<const v4f*>(h + (size_t)node * DIM + lane * 4);
    const v4f wu = *reinterpret_cast<const v4f*>(W + lane * 4);
    const v4f wv = *reinterpret_cast<const v4f*>(W + DIM + lane * 4);

    float su = hv.x * wu.x + hv.y * wu.y + hv.z * wu.z + hv.w * wu.w;
    float sv = hv.x * wv.x + hv.y * wv.y + hv.z * wv.z + hv.w * wv.w;

    // Butterfly reduce across the 32-lane group (xor masks <= 16 stay in-group).
    #pragma unroll
    for (int off = 16; off >= 1; off >>= 1) {
        su += __shfl_xor(su, off);
        sv += __shfl_xor(sv, off);
    }

    if (lane == 0) {
        pu[node] = su;
        pv[node] = sv + bias_ptr[0];   // fold bias once per node
    }
}

// Phase 2: 8 edges (2 quads) per thread, two coalesced halves; all 16 gathers
// issued before any use so their latencies overlap. pu/pv (800 KB) are
// L2/L3-resident. Only the out store is nontemporal (pure streaming write).
__global__ __launch_bounds__(256) void edge_score_kernel(
    const int*   __restrict__ src,
    const int*   __restrict__ dst,
    const float* __restrict__ pu,
    const float* __restrict__ pv,
    float* __restrict__ out)
{
    int i = blockIdx.x * blockDim.x + threadIdx.x;
    if (i >= HALFQ) return;
    int j = i + HALFQ;

    v4i s0 = reinterpret_cast<const v4i*>(src)[i];
    v4i d0 = reinterpret_cast<const v4i*>(dst)[i];
    v4i s1 = reinterpret_cast<const v4i*>(src)[j];
    v4i d1 = reinterpret_cast<const v4i*>(dst)[j];

    // 16 independent gathers in flight.
    float a00 = pu[s0.x], b00 = pv[d0.x];
    float a01 = pu[s0.y], b01 = pv[d0.y];
    float a02 = pu[s0.z], b02 = pv[d0.z];
    float a03 = pu[s0.w], b03 = pv[d0.w];
    float a10 = pu[s1.x], b10 = pv[d1.x];
    float a11 = pu[s1.y], b11 = pv[d1.y];
    float a12 = pu[s1.z], b12 = pv[d1.z];
    float a13 = pu[s1.w], b13 = pv[d1.w];

    v4f r0, r1;
    r0.x = fast_sigmoid(a00 + b00);
    r0.y = fast_sigmoid(a01 + b01);
    r0.z = fast_sigmoid(a02 + b02);
    r0.w = fast_sigmoid(a03 + b03);
    r1.x = fast_sigmoid(a10 + b10);
    r1.y = fast_sigmoid(a11 + b11);
    r1.z = fast_sigmoid(a12 + b12);
    r1.w = fast_sigmoid(a13 + b13);

    __builtin_nontemporal_store(r0, reinterpret_cast<v4f*>(out) + i);
    __builtin_nontemporal_store(r1, reinterpret_cast<v4f*>(out) + j);
}

extern "C" void kernel_launch(void* const* d_in, const int* in_sizes, int n_in,
                              void* d_out, int out_size, void* d_ws, size_t ws_size,
                              hipStream_t stream) {
    const float* h    = (const float*)d_in[0];
    const int*   src  = (const int*)d_in[1];
    const int*   dst  = (const int*)d_in[2];
    const float* W    = (const float*)d_in[3];   // (1, 256)
    const float* bias = (const float*)d_in[4];   // (1,)
    float* out = (float*)d_out;

    float* pu = (float*)d_ws;                    // NODES floats
    float* pv = pu + NODES;                      // NODES floats

    // Phase 1: 32 lanes/node -> NODES*32 threads.
    {
        int threads = 256;
        int total   = NODES * 32;
        int blocks  = (total + threads - 1) / threads;
        node_proj_kernel<<<blocks, threads, 0, stream>>>(h, W, bias, pu, pv, NODES);
    }

    // Phase 2: 8 edges/thread (2 quads), HALFQ threads.
    {
        int threads = 256;
        int blocks  = (HALFQ + threads - 1) / threads;
        edge_score_kernel<<<blocks, threads, 0, stream>>>(src, dst, pu, pv, out);
    }
}

// Round 6
// 32.494 us; speedup vs baseline: 3.6545x; 1.0079x over previous
//
#include <hip/hip_runtime.h>
#include <math.h>

#define NODES   100000
#define DIM     128
#define NEDGES  1600000          // 4 * 400000
#define NQUADS  (NEDGES / 4)     // 400000

#define LOG2E 1.44269504088896340736f

// clang-native vector types (accepted by __builtin_nontemporal_*)
typedef int   v4i __attribute__((ext_vector_type(4)));
typedef float v4f __attribute__((ext_vector_type(4)));

__device__ __forceinline__ float fast_sigmoid(float x) {
    return __builtin_amdgcn_rcpf(1.0f + __builtin_amdgcn_exp2f(-x * LOG2E));
}

__device__ __forceinline__ float dot4(v4f a, v4f b) {
    return a.x * b.x + a.y * b.y + a.z * b.z + a.w * b.w;
}

// Phase 1: pu[n] = h[n].Wu, pv[n] = h[n].Wv + bias.
// 8 lanes per node; each lane owns a 16-float column slice = 4 independent
// float4 loads = one full 64B line per lane (perfect coalescing + ILP=4).
// W slice (4 wu + 4 wv v4f) lives in registers for the whole kernel.
// 3-level shuffle reduce within the 8-lane group.
__global__ __launch_bounds__(256) void node_proj_kernel(
    const float* __restrict__ h,
    const float* __restrict__ W,      // 256 floats: Wu = W[0:128], Wv = W[128:256]
    const float* __restrict__ bias_ptr,
    float* __restrict__ pu,
    float* __restrict__ pv)
{
    const int tid   = blockIdx.x * 256 + threadIdx.x;
    const int lane8 = tid & 7;
    const int node  = tid >> 3;
    if (node >= NODES) return;

    const int c0 = lane8 * 16;                 // this lane's column base

    const v4f* __restrict__ hp = reinterpret_cast<const v4f*>(h + (size_t)node * DIM + c0);
    const v4f* __restrict__ wup = reinterpret_cast<const v4f*>(W + c0);
    const v4f* __restrict__ wvp = reinterpret_cast<const v4f*>(W + DIM + c0);

    // 4 independent h loads in flight.
    v4f h0 = hp[0], h1 = hp[1], h2 = hp[2], h3 = hp[3];
    v4f u0 = wup[0], u1 = wup[1], u2 = wup[2], u3 = wup[3];
    v4f w0 = wvp[0], w1 = wvp[1], w2 = wvp[2], w3 = wvp[3];

    float su = dot4(h0, u0) + dot4(h1, u1) + dot4(h2, u2) + dot4(h3, u3);
    float sv = dot4(h0, w0) + dot4(h1, w1) + dot4(h2, w2) + dot4(h3, w3);

    // Reduce across the 8-lane group.
    #pragma unroll
    for (int off = 4; off >= 1; off >>= 1) {
        su += __shfl_xor(su, off);
        sv += __shfl_xor(sv, off);
    }

    if (lane8 == 0) {
        pu[node] = su;
        pv[node] = sv + bias_ptr[0];           // fold bias once per node
    }
}

// Phase 2: out[e] = sigmoid(pu[src[e]] + pv[dst[e]]).
// 4 edges/thread (max TLP for the gather pipe), 8 gathers issued up front.
// pu/pv (800 KB) are L2/L3-resident. Only the out store is nontemporal.
__global__ __launch_bounds__(256) void edge_score_kernel(
    const int*   __restrict__ src,
    const int*   __restrict__ dst,
    const float* __restrict__ pu,
    const float* __restrict__ pv,
    float* __restrict__ out)
{
    int i = blockIdx.x * 256 + threadIdx.x;
    if (i >= NQUADS) return;

    v4i s4 = reinterpret_cast<const v4i*>(src)[i];
    v4i d4 = reinterpret_cast<const v4i*>(dst)[i];

    // 8 independent gathers in flight.
    float a0 = pu[s4.x], b0 = pv[d4.x];
    float a1 = pu[s4.y], b1 = pv[d4.y];
    float a2 = pu[s4.z], b2 = pv[d4.z];
    float a3 = pu[s4.w], b3 = pv[d4.w];

    v4f r;
    r.x = fast_sigmoid(a0 + b0);
    r.y = fast_sigmoid(a1 + b1);
    r.z = fast_sigmoid(a2 + b2);
    r.w = fast_sigmoid(a3 + b3);

    __builtin_nontemporal_store(r, reinterpret_cast<v4f*>(out) + i);
}

extern "C" void kernel_launch(void* const* d_in, const int* in_sizes, int n_in,
                              void* d_out, int out_size, void* d_ws, size_t ws_size,
                              hipStream_t stream) {
    const float* h    = (const float*)d_in[0];
    const int*   src  = (const int*)d_in[1];
    const int*   dst  = (const int*)d_in[2];
    const float* W    = (const float*)d_in[3];   // (1, 256)
    const float* bias = (const float*)d_in[4];   // (1,)
    float* out = (float*)d_out;

    float* pu = (float*)d_ws;                    // NODES floats
    float* pv = pu + NODES;                      // NODES floats

    // Phase 1: 8 lanes/node -> 800k threads -> 3125 blocks.
    node_proj_kernel<<<(NODES * 8) / 256, 256, 0, stream>>>(h, W, bias, pu, pv);

    // Phase 2: 4 edges/thread -> 400k threads.
    edge_score_kernel<<<(NQUADS + 255) / 256, 256, 0, stream>>>(src, dst, pu, pv, out);
}